// Round 1
// baseline (37661.038 us; speedup 1.0000x reference)
//
#include <hip/hip_runtime.h>
#include <math.h>

#define BQ 64
#define TQ 256
#define DQ 512
#define GQ 2048
#define EMBQ 511

// ---------------- embedding + predicate concat ----------------
__global__ __launch_bounds__(256) void k_embed(const int* __restrict__ wid,
                                               const int* __restrict__ pid,
                                               const float* __restrict__ emb,
                                               float* __restrict__ x) {
    int idx = blockIdx.x * 256 + threadIdx.x;  // 0 .. 8388607
    int bt = idx >> 9;                          // (b*256 + t)
    int d = idx & 511;
    float v;
    if (d < EMBQ) v = emb[(size_t)wid[bt] * EMBQ + d];
    else          v = (float)pid[bt];
    x[idx] = v;
}

// ---------------- pre = xi @ W + b  (chunk of time steps) ----------------
// grid: (CHUNK, 32). blockIdx.x = s_local (one time step = 64 batch rows),
// blockIdx.y = n-tile (64 cols). 64x64 tile, 256 thr, 4x4 per thread.
__global__ __launch_bounds__(256) void k_pre(const float* __restrict__ x,
                                             const float* __restrict__ W,
                                             const float* __restrict__ bias,
                                             float* __restrict__ pre,
                                             int s0, int flip) {
    __shared__ float As[16][68];
    __shared__ float Bs[16][68];
    int mt = blockIdx.x;            // s_local
    int nt = blockIdx.y;
    int tid = threadIdx.x;
    int s = s0 + mt;
    int t_in = flip ? (TQ - 1 - s) : s;

    int tr = tid >> 4;              // 0..15
    int tc = tid & 15;              // 0..15
    float acc[4][4];
#pragma unroll
    for (int i = 0; i < 4; ++i)
#pragma unroll
        for (int j = 0; j < 4; ++j) acc[i][j] = 0.f;

    int am = tid >> 2;              // 0..63 (batch row)
    int akq = (tid & 3) * 4;        // 0..12
    int bk = tid >> 4;              // 0..15
    int bnq = (tid & 15) * 4;       // 0..60

    const float* xrow = x + (size_t)(am * TQ + t_in) * DQ;

    for (int kt = 0; kt < DQ; kt += 16) {
        float4 a4 = *(const float4*)&xrow[kt + akq];
        As[akq + 0][am] = a4.x;
        As[akq + 1][am] = a4.y;
        As[akq + 2][am] = a4.z;
        As[akq + 3][am] = a4.w;
        float4 b4 = *(const float4*)&W[(size_t)(kt + bk) * GQ + nt * 64 + bnq];
        *(float4*)&Bs[bk][bnq] = b4;
        __syncthreads();
#pragma unroll
        for (int k = 0; k < 16; ++k) {
            float4 av = *(const float4*)&As[k][tr * 4];
            float4 bv = *(const float4*)&Bs[k][tc * 4];
            float a[4] = {av.x, av.y, av.z, av.w};
            float b[4] = {bv.x, bv.y, bv.z, bv.w};
#pragma unroll
            for (int i = 0; i < 4; ++i)
#pragma unroll
                for (int j = 0; j < 4; ++j) acc[i][j] += a[i] * b[j];
        }
        __syncthreads();
    }
#pragma unroll
    for (int i = 0; i < 4; ++i) {
        int b = tr * 4 + i;
#pragma unroll
        for (int j = 0; j < 4; ++j) {
            int n = nt * 64 + tc * 4 + j;
            pre[(size_t)(mt * 64 + b) * GQ + n] = acc[i][j] + bias[n];
        }
    }
}

// ---------------- one LSTM step: z = pre + h@U ; gates ; masked update ----
// grid: 128 WGs. wg -> cg = wg>>2 (16 h-cols), bg = wg&3 (16 batch rows).
// 4 waves = 4 k-quarters; lane l -> z-col = (l>>4)*512 + cg*16 + (l&15).
__global__ __launch_bounds__(256) void k_step(const float* __restrict__ U,
                                              const float* __restrict__ pre,
                                              const float* __restrict__ h_in,
                                              float* __restrict__ h_out,
                                              float* __restrict__ c,
                                              float* __restrict__ xn,
                                              const int* __restrict__ mask,
                                              int s_local, int s, int flip) {
    int wg = blockIdx.x;
    int cg = wg >> 2;
    int bg = wg & 3;
    int tid = threadIdx.x;
    int w = tid >> 6;               // k-quarter
    int l = tid & 63;
    int col = ((l >> 4) * DQ) + cg * 16 + (l & 15);

    float acc[16];
#pragma unroll
    for (int i = 0; i < 16; ++i) acc[i] = 0.f;

    const float* hb = h_in + (size_t)bg * 16 * DQ;
    int k0 = w * 128;
    for (int k = k0; k < k0 + 128; ++k) {
        float uv = U[(size_t)k * GQ + col];
#pragma unroll
        for (int i = 0; i < 16; ++i) acc[i] += hb[i * DQ + k] * uv;
    }

    __shared__ float part[4][16][64];
#pragma unroll
    for (int i = 0; i < 16; ++i) part[w][i][l] = acc[i];
    __syncthreads();

    int bsub = tid >> 4;            // 0..15
    int hsub = tid & 15;            // 0..15
    int b = bg * 16 + bsub;
    int hc = cg * 16 + hsub;

    float z[4];
#pragma unroll
    for (int g = 0; g < 4; ++g) {
        float zz = pre[(size_t)(s_local * 64 + b) * GQ + g * DQ + hc];
#pragma unroll
        for (int ww = 0; ww < 4; ++ww) zz += part[ww][bsub][g * 16 + hsub];
        z[g] = zz;
    }
    float ig = 1.f / (1.f + expf(-z[0]));
    float fg = 1.f / (1.f + expf(-z[1]));
    float gg = tanhf(z[2]);
    float og = 1.f / (1.f + expf(-z[3]));

    float c_old = c[b * DQ + hc];
    float h_old = h_in[b * DQ + hc];
    float cn = fg * c_old + ig * gg;
    float hn = og * tanhf(cn);

    int t_in = flip ? (TQ - 1 - s) : s;
    int mt = mask[b * TQ + t_in];
    float ho = mt ? hn : h_old;
    float co = mt ? cn : c_old;

    h_out[b * DQ + hc] = ho;
    c[b * DQ + hc] = co;
    xn[(size_t)(b * TQ + s) * DQ + hc] = ho;
}

// ---------------- logits = x @ Wout + bout ----------------
__global__ __launch_bounds__(256) void k_out(const float* __restrict__ x,
                                             const float* __restrict__ Wo,
                                             const float* __restrict__ bo,
                                             float* __restrict__ out) {
    int r = blockIdx.x * 4 + (threadIdx.x >> 6);
    int n = threadIdx.x & 63;
    const float* xr = x + (size_t)r * DQ;
    float acc = bo[n];
    for (int k = 0; k < DQ; ++k) acc += xr[k] * Wo[k * 64 + n];
    out[(size_t)r * 64 + n] = acc;
}

extern "C" void kernel_launch(void* const* d_in, const int* in_sizes, int n_in,
                              void* d_out, int out_size, void* d_ws, size_t ws_size,
                              hipStream_t stream) {
    const int*   wid  = (const int*)d_in[0];
    const int*   pid  = (const int*)d_in[1];
    const int*   mask = (const int*)d_in[2];
    const float* emb  = (const float*)d_in[3];
    const float* Ws   = (const float*)d_in[4];
    const float* Us   = (const float*)d_in[5];
    const float* bs   = (const float*)d_in[6];
    const float* Wo   = (const float*)d_in[7];
    const float* bo   = (const float*)d_in[8];
    float* out = (float*)d_out;

    float* x0 = (float*)d_ws;                 // [64*256*512]
    float* x1 = x0 + (size_t)8388608;         // [64*256*512]
    float* hA = x1 + (size_t)8388608;         // [64*512]
    float* cc = hA + 32768;                   // [64*512]
    float* hB = cc + 32768;                   // [64*512]
    float* pre = hB + 32768;                  // [CHUNK*64*2048]

    size_t base_bytes = ((size_t)8388608 * 2 + 3 * 32768) * 4;
    int CHUNK = 256;
    while (CHUNK > 1 && base_bytes + (size_t)CHUNK * 131072 * 4 > ws_size) CHUNK >>= 1;

    k_embed<<<32768, 256, 0, stream>>>(wid, pid, emb, x0);

    float* xc = x0;
    float* xn = x1;
    for (int layer = 0; layer < 4; ++layer) {
        int flip = layer & 1;
        const float* W = Ws + (size_t)layer * DQ * GQ;
        const float* U = Us + (size_t)layer * DQ * GQ;
        const float* bias = bs + (size_t)layer * GQ;
        // zero h (hA) and c (adjacent) in one memset
        hipMemsetAsync(hA, 0, (size_t)2 * 32768 * 4, stream);
        float* hin = hA;
        float* hout = hB;
        for (int s0 = 0; s0 < TQ; s0 += CHUNK) {
            dim3 g(CHUNK, 32);
            k_pre<<<g, 256, 0, stream>>>(xc, W, bias, pre, s0, flip);
            for (int s = s0; s < s0 + CHUNK; ++s) {
                k_step<<<128, 256, 0, stream>>>(U, pre, hin, hout, cc, xn, mask,
                                                s - s0, s, flip);
                float* t = hin; hin = hout; hout = t;
            }
        }
        float* t = xc; xc = xn; xn = t;
    }

    k_out<<<4096, 256, 0, stream>>>(xc, Wo, bo, out);
}